// Round 9
// baseline (484.974 us; speedup 1.0000x reference)
//
#include <hip/hip_runtime.h>
#include <hip/hip_bf16.h>

// Problem constants
#define BN 262144
#define DD 64
#define KC 1024
#define HB2 2048         // hist/scatter blocks (fused hist: = pass1 grid)
#define RPB 128          // rows per hist/scatter block

// ---- Output layout (FLOAT32 elements), reference tuple return order ----
// codes [B] | quantized [B*D] | residuals [B*D] | loss [1] | new_emb [K*D]
// | new_cluster_size [K] | new_embed_sum [K*D]
#define OUT_Q_OFF   (BN)
#define OUT_R_OFF   (BN + BN * DD)
#define OUT_LOSS    (BN + 2 * BN * DD)

// ---- Scratch overlay (element offsets into S = out + OUT_Q_OFF, the
// quantized slab, 64 MB). Consumed before vq_pass2 overwrites.
#define S_LOSS      0                         // (unused; loss now in pass2)
#define S_ENORM     4                         // (reserved)
#define S_ENORM64   (S_ENORM + KC)            // KC f64 (2*KC f32 slots; 8B-aligned)
#define S_COUNT     (S_ENORM64 + 2 * KC)      // KC i32
#define S_OFFSET    (S_COUNT + KC)            // KC i32 (exclusive prefix)
#define S_BLOCKHIST (S_OFFSET + KC)           // HB2*KC i32
#define S_BASE      (S_BLOCKHIST + HB2 * KC)  // HB2*KC i32 (pre-offset)
#define S_PERM      (S_BASE + HB2 * KC)       // BN i32
#define S_NTIE      (S_PERM + BN)             // 1 i32 (+3 pad)
#define S_TIES      (S_NTIE + 4)              // up to BN i32
// Packed, pre-swizzled codebook: 16 tiles x 16640 B
//   per tile: [0,8K) eh swizzled | [8K,16K) el swizzled | [16K,16.25K) -en/2
#define S_EPACK     (((S_TIES + BN) + 3) & ~3)
#define TILE_BYTES  16640
#define S_PART      (S_EPACK + 16 * TILE_BYTES / 4)  // 8*KC*DD f32 reduce partials
// total overlay ~21 MB << 64 MB slab

// fp16-split dist worst-case error ~1e-4 (lo terms are 2^-23-scale; MFMA
// accumulates fp32). Margin 8e-4 keeps ~8x cushion. r8 lesson: margin 2e-3
// flagged ~1-2% of rows -> resolve burned ~40-50us of L2 emb re-scans.
#define TIE_MARGIN 8e-4f

typedef _Float16 f16x8 __attribute__((ext_vector_type(8)));
typedef float    f32x4 __attribute__((ext_vector_type(4)));

__device__ inline f32x4 shflx4(f32x4 v, int m) {
    f32x4 r;
    r[0] = __shfl_xor(v[0], m, 64);
    r[1] = __shfl_xor(v[1], m, 64);
    r[2] = __shfl_xor(v[2], m, 64);
    r[3] = __shfl_xor(v[3], m, 64);
    return r;
}

__device__ inline void gl_lds16(const void* g, void* l) {
    __builtin_amdgcn_global_load_lds(
        (const __attribute__((address_space(1))) void*)g,
        (__attribute__((address_space(3))) void*)l, 16, 0, 0);
}

// Init (parallel, 32 blocks): 8 lanes per codebook row, one 8-elem chunk each.
// Zero loss/tie-counter, |e_k|^2 fp64 (shfl-reduced), packed pre-swizzled
// fp16 hi/lo codebook (lo scaled 2^11; swizzle = LDS layout of pass1).
__global__ __launch_bounds__(256) void vq_init(const float* __restrict__ emb,
                                               float* __restrict__ S,
                                               float* __restrict__ out_loss) {
    const int t = threadIdx.x;
    const int g = blockIdx.x * 256 + t;
    if (g == 0) { out_loss[0] = 0.0f; ((int*)(S + S_NTIE))[0] = 0; }
    const int i = g >> 3;        // codebook row (32 blocks x 256 / 8 = 1024)
    const int q = g & 7;         // 8-element chunk within the row
    const float4* e4 = (const float4*)(emb + (size_t)i * DD);
    char* tb = (char*)(S + S_EPACK) + (size_t)(i >> 6) * TILE_BYTES;
    const int ci = i & 63;
    const int sw = (ci & 7) * 8;

    float4 u = e4[2 * q], v = e4[2 * q + 1];
    float a = u.x * u.x;
    a = fmaf(u.y, u.y, a); a = fmaf(u.z, u.z, a); a = fmaf(u.w, u.w, a);
    a = fmaf(v.x, v.x, a); a = fmaf(v.y, v.y, a);
    a = fmaf(v.z, v.z, a); a = fmaf(v.w, v.w, a);
    double b = (double)u.x * u.x + (double)u.y * u.y
             + (double)u.z * u.z + (double)u.w * u.w
             + (double)v.x * v.x + (double)v.y * v.y
             + (double)v.z * v.z + (double)v.w * v.w;

    f16x8 hh, ll;
    hh[0] = (_Float16)u.x; hh[1] = (_Float16)u.y;
    hh[2] = (_Float16)u.z; hh[3] = (_Float16)u.w;
    hh[4] = (_Float16)v.x; hh[5] = (_Float16)v.y;
    hh[6] = (_Float16)v.z; hh[7] = (_Float16)v.w;
    ll[0] = (_Float16)((u.x - (float)hh[0]) * 2048.f);
    ll[1] = (_Float16)((u.y - (float)hh[1]) * 2048.f);
    ll[2] = (_Float16)((u.z - (float)hh[2]) * 2048.f);
    ll[3] = (_Float16)((u.w - (float)hh[3]) * 2048.f);
    ll[4] = (_Float16)((v.x - (float)hh[4]) * 2048.f);
    ll[5] = (_Float16)((v.y - (float)hh[5]) * 2048.f);
    ll[6] = (_Float16)((v.z - (float)hh[6]) * 2048.f);
    ll[7] = (_Float16)((v.w - (float)hh[7]) * 2048.f);
    const int u16 = (ci * 64 + q * 8) ^ sw;   // swizzled ushort idx
    *(f16x8*)(tb + 2 * u16) = hh;
    *(f16x8*)(tb + 8192 + 2 * u16) = ll;

    // reduce |e|^2 across the 8 lanes of this row (xor 1,2,4 stays in-row)
#pragma unroll
    for (int off = 1; off <= 4; off <<= 1) {
        a += __shfl_xor(a, off, 64);
        b += __shfl_xor(b, off, 64);
    }
    if (q == 0) {
        *(float*)(tb + 16384 + ci * 4) = -0.5f * a;   // MFMA C seed
        ((double*)(S + S_ENORM64))[i] = b;
    }
}

// Pass 1 (MFMA, pipelined) + FUSED per-block histogram.
// 4 waves/block, 32 rows/wave (128 rows/block). Best-measured schedule
// (r6/r8: 143-148us, VGPR 100, 4 blocks/CU). mi=4 regressed (r5); min-waves
// bound spills (r3). Codebook staged per 64-code tile via async
// global_load_lds, double buffer, counted vmcnt(5) + raw s_barrier.
// dist tracked in maximize domain m = dot - |e|^2/2 (seeded via MFMA C).
// Hist: LDS counters over this block's 128 final codes -> blockhist[block].
__global__ __launch_bounds__(256) void vq_pass1(
    const float* __restrict__ x,
    float* __restrict__ S,
    float* __restrict__ out_codes) {
    __shared__ __align__(16) unsigned char raw[2 * TILE_BYTES];
    __shared__ int lh[KC];

    const int t = threadIdx.x;
    const int lane = t & 63, wid = t >> 6;
    const int c = lane & 15, g = lane >> 4;
    const int rowbase = blockIdx.x * 128 + wid * 32;
    const char* epack = (const char*)(S + S_EPACK);

#pragma unroll
    for (int j = 0; j < 4; ++j) lh[t + 256 * j] = 0;   // hist zero (synced by
                                                       // the kt-loop barriers)

    // ---- stage tile 0 (prologue, async) ----
    {
        const char* st = epack;                 // tile 0
#pragma unroll
        for (int cc = 0; cc < 4; ++cc) {
            const int chunk = wid * 260 + cc * 64;
            gl_lds16(st + (size_t)(chunk + lane) * 16, raw + chunk * 16);
        }
        const int chunk = wid * 260 + 256;
        if (lane < 4)
            gl_lds16(st + (size_t)(chunk + lane) * 16, raw + chunk * 16);
    }

    // ---- load + convert x fragments (overlaps tile-0 staging) ----
    f16x8 a_hi[2][2], a_lo[2][2];
#pragma unroll
    for (int mi = 0; mi < 2; ++mi) {
        const float4* xr = (const float4*)(x + (size_t)(rowbase + mi * 16 + c) * DD);
#pragma unroll
        for (int h = 0; h < 2; ++h) {
            float4 u = xr[h * 8 + g * 2];
            float4 v = xr[h * 8 + g * 2 + 1];
            f16x8 hi, lo;
            hi[0] = (_Float16)u.x; hi[1] = (_Float16)u.y;
            hi[2] = (_Float16)u.z; hi[3] = (_Float16)u.w;
            hi[4] = (_Float16)v.x; hi[5] = (_Float16)v.y;
            hi[6] = (_Float16)v.z; hi[7] = (_Float16)v.w;
            lo[0] = (_Float16)((u.x - (float)hi[0]) * 2048.f);
            lo[1] = (_Float16)((u.y - (float)hi[1]) * 2048.f);
            lo[2] = (_Float16)((u.z - (float)hi[2]) * 2048.f);
            lo[3] = (_Float16)((u.w - (float)hi[3]) * 2048.f);
            lo[4] = (_Float16)((v.x - (float)hi[4]) * 2048.f);
            lo[5] = (_Float16)((v.y - (float)hi[5]) * 2048.f);
            lo[6] = (_Float16)((v.z - (float)hi[6]) * 2048.f);
            lo[7] = (_Float16)((v.w - (float)hi[7]) * 2048.f);
            a_hi[mi][h] = hi;
            a_lo[mi][h] = lo;
        }
    }

    // top-2 state in maximize domain (m bigger = closer); slot s = mi*4+r
    float b1[8], b2[8];
    int kb[8];
#pragma unroll
    for (int s = 0; s < 8; ++s) { b1[s] = -3.4e38f; b2[s] = -3.4e38f; kb[s] = 0; }

    // LDS read byte bases (swizzle folded; per-ni deltas are imm offsets)
    const int sw = (c & 7) * 8;
    const int bb0 = 2 * ((c * 64 + g * 8) ^ sw);
    const int bb1 = 2 * ((c * 64 + 32 + g * 8) ^ sw);
    const int be = 16384 + c * 4;

#pragma unroll 2
    for (int kt = 0; kt < 16; ++kt) {
        // issue next tile's staging loads, then wait for CURRENT tile only
        if (kt < 15) {
            const char* st = epack + (size_t)(kt + 1) * TILE_BYTES;
            unsigned char* db = raw + ((kt + 1) & 1) * TILE_BYTES;
#pragma unroll
            for (int cc = 0; cc < 4; ++cc) {
                const int chunk = wid * 260 + cc * 64;
                gl_lds16(st + (size_t)(chunk + lane) * 16, db + chunk * 16);
            }
            const int chunk = wid * 260 + 256;
            if (lane < 4)
                gl_lds16(st + (size_t)(chunk + lane) * 16, db + chunk * 16);
            __builtin_amdgcn_sched_barrier(0);
            asm volatile("s_waitcnt vmcnt(5)");
        } else {
            __builtin_amdgcn_sched_barrier(0);
            asm volatile("s_waitcnt vmcnt(0)");
        }
        __builtin_amdgcn_sched_barrier(0);
        __builtin_amdgcn_s_barrier();

        const unsigned char* bufp = raw + (kt & 1) * TILE_BYTES;
        const int kbase = kt * 64;
#pragma unroll
        for (int ni = 0; ni < 4; ++ni) {
            f16x8 bh0 = *(const f16x8*)(bufp + bb0 + ni * 2048);
            f16x8 bh1 = *(const f16x8*)(bufp + bb1 + ni * 2048);
            f16x8 bl0 = *(const f16x8*)(bufp + 8192 + bb0 + ni * 2048);
            f16x8 bl1 = *(const f16x8*)(bufp + 8192 + bb1 + ni * 2048);
            const float seed = *(const float*)(bufp + be + ni * 64);
            const int kcur = kbase + ni * 16 + c;
#pragma unroll
            for (int mi = 0; mi < 2; ++mi) {
                f32x4 ah = {seed, seed, seed, seed};
                f32x4 ax = {0.f, 0.f, 0.f, 0.f};
                ah = __builtin_amdgcn_mfma_f32_16x16x32_f16(a_hi[mi][0], bh0, ah, 0, 0, 0);
                ah = __builtin_amdgcn_mfma_f32_16x16x32_f16(a_hi[mi][1], bh1, ah, 0, 0, 0);
                ax = __builtin_amdgcn_mfma_f32_16x16x32_f16(a_hi[mi][0], bl0, ax, 0, 0, 0);
                ax = __builtin_amdgcn_mfma_f32_16x16x32_f16(a_lo[mi][0], bh0, ax, 0, 0, 0);
                ax = __builtin_amdgcn_mfma_f32_16x16x32_f16(a_hi[mi][1], bl1, ax, 0, 0, 0);
                ax = __builtin_amdgcn_mfma_f32_16x16x32_f16(a_lo[mi][1], bh1, ax, 0, 0, 0);
#pragma unroll
                for (int r = 0; r < 4; ++r) {
                    // m = dot - |e|^2/2  (dist = -2m)
                    const float m = fmaf(4.8828125e-4f, ax[r], ah[r]);
                    const int s = mi * 4 + r;
                    // second-best: b2' = median(m, b1, b2)  (b2 <= b1 invariant)
                    b2[s] = __builtin_amdgcn_fmed3f(m, b1[s], b2[s]);
                    const bool gt = m > b1[s];
                    b1[s] = fmaxf(b1[s], m);
                    kb[s] = gt ? kcur : kb[s];
                }
            }
        }
        __builtin_amdgcn_s_barrier();
    }

    // merge top-2 across the 16 col-lanes of each row-group (same lane>>4)
#pragma unroll
    for (int off = 1; off <= 8; off <<= 1) {
#pragma unroll
        for (int s = 0; s < 8; ++s) {
            float ob1 = __shfl_xor(b1[s], off, 64);
            float ob2 = __shfl_xor(b2[s], off, 64);
            int okk = __shfl_xor(kb[s], off, 64);
            float mn = fminf(b1[s], ob1);
            b2[s] = fmaxf(fmaxf(b2[s], ob2), mn);
            if (ob1 > b1[s]) { b1[s] = ob1; kb[s] = okk; }
        }
    }

    const int rlo = c - g * 4;   // writer lanes: c in [4g, 4g+4)
    if (rlo >= 0 && rlo < 4) {
        int* ntie = (int*)(S + S_NTIE);
        int* ties = (int*)(S + S_TIES);
#pragma unroll
        for (int mi = 0; mi < 2; ++mi) {
            const int s = mi * 4 + rlo;
            const int row = rowbase + mi * 16 + c;
            out_codes[row] = (float)kb[s];
            atomicAdd(&lh[kb[s]], 1);            // fused hist (LDS)
            if ((b1[s] - b2[s]) * 2.0f < TIE_MARGIN) {
                int slot = atomicAdd(ntie, 1);
                ties[slot] = row;
            }
        }
    }
    __syncthreads();
    int* bh = (int*)(S + S_BLOCKHIST) + (size_t)blockIdx.x * KC;
#pragma unroll
    for (int j = 0; j < 4; ++j) bh[t + 256 * j] = lh[t + 256 * j];
}

// Tie resolve: wave per flagged row, full fp64 argmin over K (16 codes/lane).
// Strictly stronger than candidate-limited resolve; first-k wins exact ties.
// Patches the fused blockhist when the code changes (runs before scan1).
__global__ __launch_bounds__(256) void vq_resolve(
    const float* __restrict__ x,
    const float* __restrict__ emb,
    float* __restrict__ S,
    float* __restrict__ out_codes) {
    const int n = ((const int*)(S + S_NTIE))[0];
    const int* ties = (const int*)(S + S_TIES);
    const double* en64 = (const double*)(S + S_ENORM64);
    int* bh = (int*)(S + S_BLOCKHIST);
    const int lane = threadIdx.x & 63;
    const int gw = (blockIdx.x * 256 + threadIdx.x) >> 6;
    const int nw = (gridDim.x * 256) >> 6;
    for (int i = gw; i < n; i += nw) {
        const int row = ties[i];
        const int oldk = (int)out_codes[row];
        const float4* xr = (const float4*)(x + (size_t)row * DD);
        float4 xq[16];
#pragma unroll
        for (int j = 0; j < 16; ++j) xq[j] = xr[j];
        double bd = 1e300;
        int bk = KC;
        for (int kk = 0; kk < KC / 64; ++kk) {
            const int k = lane * (KC / 64) + kk;   // ascending within lane
            const float4* er = (const float4*)(emb + (size_t)k * DD);
            double d0 = 0., d1 = 0., d2 = 0., d3 = 0.;
#pragma unroll
            for (int j = 0; j < 16; ++j) {
                float4 e = er[j], xv = xq[j];
                d0 = fma((double)xv.x, (double)e.x, d0);
                d1 = fma((double)xv.y, (double)e.y, d1);
                d2 = fma((double)xv.z, (double)e.z, d2);
                d3 = fma((double)xv.w, (double)e.w, d3);
            }
            double dist = en64[k] - 2.0 * ((d0 + d1) + (d2 + d3));
            if (dist < bd) { bd = dist; bk = k; }
        }
#pragma unroll
        for (int off = 32; off; off >>= 1) {
            double od = __shfl_xor(bd, off, 64);
            int ok = __shfl_xor(bk, off, 64);
            if (od < bd || (od == bd && ok < bk)) { bd = od; bk = ok; }
        }
        if (lane == 0 && bk != oldk) {
            out_codes[row] = (float)bk;
            const int b = row >> 7;                     // 128 rows/hist block
            atomicAdd(&bh[(size_t)b * KC + oldk], -1);
            atomicAdd(&bh[(size_t)b * KC + bk], 1);
        }
    }
}

// Scan 1: column-parallel prefix over the HB2 blockhists (coalesced), and
// per-code totals. 16 blocks x 64 threads = one thread per code column.
__global__ __launch_bounds__(64) void vq_scan1(float* S) {
    const int k = blockIdx.x * 64 + threadIdx.x;
    int* blockhist = (int*)(S + S_BLOCKHIST);
    int* base      = (int*)(S + S_BASE);
    int* count     = (int*)(S + S_COUNT);
    int s = 0;
#pragma unroll 8
    for (int b = 0; b < HB2; ++b) {
        base[(size_t)b * KC + k] = s;    // in-block running start (pre-offset)
        s += blockhist[(size_t)b * KC + k];
    }
    count[k] = s;
}

// Scan 2: exclusive prefix over K of the counts -> offset. Single block.
// (The base+offset add is folded into vq_scatter's cursor init.)
__global__ __launch_bounds__(1024) void vq_scan2(float* S) {
    __shared__ int sc[KC];
    const int k = threadIdx.x;
    int* count  = (int*)(S + S_COUNT);
    int* offset = (int*)(S + S_OFFSET);
    sc[k] = count[k];
    __syncthreads();
    for (int st = 1; st < KC; st <<= 1) {
        int v = (k >= st) ? sc[k - st] : 0;
        __syncthreads();
        sc[k] += v;
        __syncthreads();
    }
    offset[k] = (k == 0) ? 0 : sc[k - 1];  // exclusive
}

// Scatter: LDS cursors (LDS atomics only) -> perm row-index lists.
// 2048 blocks x 128 rows (matches fused-hist partitioning). Cursor init
// folds the global offset.
__global__ __launch_bounds__(128) void vq_scatter(const float* __restrict__ codes,
                                                  float* S) {
    __shared__ int cur[KC];
    const int b = blockIdx.x, t = threadIdx.x;
    int* base   = (int*)(S + S_BASE);
    int* offset = (int*)(S + S_OFFSET);
    int* perm   = (int*)(S + S_PERM);
#pragma unroll
    for (int j = 0; j < 8; ++j) {
        int k = t + 128 * j;
        cur[k] = base[(size_t)b * KC + k] + offset[k];
    }
    __syncthreads();
    {
        int row = b * RPB + t;
        int k = (int)codes[row];
        int slot = atomicAdd(&cur[k], 1);   // LDS atomic
        perm[slot] = row;
    }
}

// Reduce: grid = KC*8 (code k = blockIdx>>3, sub-range = blockIdx&7).
// Wave layout: 4 rows in flight (l>>4) x 16 float4 dim-segs (l&15).
// Plain-store deterministic partials to S_PART; vq_emafin combines.
__global__ __launch_bounds__(256) void vq_reduce(
    const float* __restrict__ x,
    float* __restrict__ S) {
    __shared__ f32x4 part[4][16];
    const int k = blockIdx.x >> 3, sub = blockIdx.x & 7;
    const int t = threadIdx.x, l = t & 63, w = t >> 6;
    const int rg = l >> 4, ds = l & 15;
    const int* count  = (const int*)(S + S_COUNT);
    const int* offset = (const int*)(S + S_OFFSET);
    const int* perm   = (const int*)(S + S_PERM);

    const int n = count[k], start = offset[k];
    const int nb = (n + 7) >> 3;
    int cnt = n - sub * nb;
    cnt = cnt < nb ? cnt : nb;               // may be <= 0
    const int s0 = start + sub * nb;
    const int s1 = s0 + cnt;

    f32x4 a0 = {0.f, 0.f, 0.f, 0.f}, a1 = a0, a2 = a0, a3 = a0;
    const int base = s0 + w * 4 + rg;
    const int iters = (cnt + 63) >> 6;       // uniform per block
#pragma unroll 2
    for (int it = 0; it < iters; ++it) {
        const int j = base + it * 64;
        const int r0 = (j      < s1) ? perm[j]      : -1;
        const int r1 = (j + 16 < s1) ? perm[j + 16] : -1;
        const int r2 = (j + 32 < s1) ? perm[j + 32] : -1;
        const int r3 = (j + 48 < s1) ? perm[j + 48] : -1;
        if (r0 >= 0) a0 += *(const f32x4*)(x + (size_t)r0 * DD + ds * 4);
        if (r1 >= 0) a1 += *(const f32x4*)(x + (size_t)r1 * DD + ds * 4);
        if (r2 >= 0) a2 += *(const f32x4*)(x + (size_t)r2 * DD + ds * 4);
        if (r3 >= 0) a3 += *(const f32x4*)(x + (size_t)r3 * DD + ds * 4);
    }
    f32x4 acc = (a0 + a1) + (a2 + a3);
    acc += shflx4(acc, 16);
    acc += shflx4(acc, 32);
    if (l < 16) part[w][l] = acc;
    __syncthreads();
    if (t < 16) {
        f32x4 tot = (part[0][t] + part[1][t]) + (part[2][t] + part[3][t]);
        ((f32x4*)(S + S_PART))[((size_t)sub * KC + k) * 16 + t] = tot;
    }
}

// EMA epilogue: combine 8 partials, EMA update, division, ncs.
__global__ __launch_bounds__(256) void vq_emafin(
    const float* __restrict__ S,
    const float* __restrict__ ema_cs,
    const float* __restrict__ ema_es,
    float* __restrict__ out_ne,
    float* __restrict__ out_ncs,
    float* __restrict__ out_nes) {
    const int i = blockIdx.x * 256 + threadIdx.x;
    const int* count = (const int*)(S + S_COUNT);
    const int NV = KC * DD / 4;              // 16384 float4s
    if (i < NV) {
        const f32x4* P = (const f32x4*)(S + S_PART);
        f32x4 s = ((P[i] + P[NV + i]) + (P[2 * NV + i] + P[3 * NV + i]))
                + ((P[4 * NV + i] + P[5 * NV + i]) + (P[6 * NV + i] + P[7 * NV + i]));
        f32x4 e = ((const f32x4*)ema_es)[i];
        const int k = i >> 4;
        const float cs = 0.99f * ema_cs[k] + 0.01f * (float)count[k];
        const float mx = fmaxf(cs, 1e-5f);
        f32x4 nes = e * 0.99f + s * 0.01f;
        f32x4 ne;
        ne[0] = nes[0] / mx; ne[1] = nes[1] / mx;
        ne[2] = nes[2] / mx; ne[3] = nes[3] / mx;
        ((f32x4*)out_nes)[i] = nes;
        ((f32x4*)out_ne)[i] = ne;
    } else if (i < NV + KC) {
        const int k = i - NV;
        out_ncs[k] = 0.99f * ema_cs[k] + 0.01f * (float)count[k];
    }
}

// Pass 2 (coalesced, atomic-lean): 1024 blocks x 256 rows. lane = (row-group,
// float4 seg) -> each wave access is a contiguous 1KB line; 16 deep ILP per
// thread. Loss: wave shuffle-reduce -> LDS -> ONE atomic per block.
// r7 lesson: 16384 same-address device atomics serialized (~12ns each) and
// dominated (215us, 794GB/s, VALU 1.7%). 1024 atomics hide under traffic.
__global__ __launch_bounds__(256) void vq_pass2(
    const float* __restrict__ x,
    const float* __restrict__ emb,
    const float* __restrict__ out_codes,
    float4* __restrict__ out_q,
    float4* __restrict__ out_r,
    float* __restrict__ out_loss) {
    __shared__ float lpart[4];
    const int t = threadIdx.x;
    const int seg = t & 15, rr = t >> 4;    // rr in 0..15
    const int rowbase = blockIdx.x * 256;
    float lsum = 0.f;
#pragma unroll
    for (int it = 0; it < 16; ++it) {
        const int row = rowbase + it * 16 + rr;
        const int code = (int)out_codes[row];
        const float4 xv = ((const float4*)x)[(size_t)row * 16 + seg];
        const float4 e  = ((const float4*)emb)[(size_t)code * 16 + seg];
        float4 q, r;
        q.x = xv.x + (e.x - xv.x); q.y = xv.y + (e.y - xv.y);
        q.z = xv.z + (e.z - xv.z); q.w = xv.w + (e.w - xv.w);
        r.x = xv.x - e.x; r.y = xv.y - e.y; r.z = xv.z - e.z; r.w = xv.w - e.w;
        lsum += r.x * r.x + r.y * r.y + r.z * r.z + r.w * r.w;
        out_q[(size_t)row * 16 + seg] = q;
        out_r[(size_t)row * 16 + seg] = r;
    }
#pragma unroll
    for (int off = 32; off; off >>= 1) lsum += __shfl_xor(lsum, off, 64);
    if ((t & 63) == 0) lpart[t >> 6] = lsum;
    __syncthreads();
    if (t == 0) {
        float tot = (lpart[0] + lpart[1]) + (lpart[2] + lpart[3]);
        atomicAdd(out_loss, tot * 1.25f * (1.0f / 16777216.0f));
    }
}

extern "C" void kernel_launch(void* const* d_in, const int* in_sizes, int n_in,
                              void* d_out, int out_size, void* d_ws, size_t ws_size,
                              hipStream_t stream) {
    const float* x      = (const float*)d_in[0];
    const float* emb    = (const float*)d_in[1];
    const float* ema_cs = (const float*)d_in[2];
    const float* ema_es = (const float*)d_in[3];

    float* out = (float*)d_out;
    float*  out_codes = out;
    float4* out_q     = (float4*)(out + OUT_Q_OFF);
    float4* out_r     = (float4*)(out + OUT_R_OFF);
    float*  out_loss  = out + OUT_LOSS;
    float*  out_ne    = out_loss + 1;
    float*  out_ncs   = out_ne + KC * DD;
    float*  out_nes   = out_ncs + KC;

    float* S = out + OUT_Q_OFF;   // scratch overlay in quantized slab

    vq_init<<<32, 256, 0, stream>>>(emb, S, out_loss);
    vq_pass1<<<BN / 128, 256, 0, stream>>>(x, S, out_codes);
    vq_resolve<<<256, 256, 0, stream>>>(x, emb, S, out_codes);
    vq_scan1<<<KC / 64, 64, 0, stream>>>(S);
    vq_scan2<<<1, 1024, 0, stream>>>(S);
    vq_scatter<<<HB2, 128, 0, stream>>>(out_codes, S);
    vq_reduce<<<KC * 8, 256, 0, stream>>>(x, S);
    vq_emafin<<<(KC * DD / 4 + KC + 255) / 256, 256, 0, stream>>>(
        S, ema_cs, ema_es, out_ne, out_ncs, out_nes);
    vq_pass2<<<BN / 256, 256, 0, stream>>>(x, emb, out_codes, out_q, out_r,
                                           out_loss);
}

// Round 10
// 402.946 us; speedup vs baseline: 1.2036x; 1.2036x over previous
//
#include <hip/hip_runtime.h>
#include <hip/hip_bf16.h>

// Problem constants
#define BN 262144
#define DD 64
#define KC 1024
#define HB 256           // histogram/scatter blocks (full CU coverage)
#define ROWS_PER_HB (BN / HB)   // 1024
// r9 lesson: fusing hist into pass1 (2048 hist blocks) starved scan1/scatter
// of parallelism (16-CU serial walk over 16MB) and cost +80us net. Separate
// HB=256 hist + wide scan is faster despite the extra launch.

// ---- Output layout (FLOAT32 elements), reference tuple return order ----
// codes [B] | quantized [B*D] | residuals [B*D] | loss [1] | new_emb [K*D]
// | new_cluster_size [K] | new_embed_sum [K*D]
#define OUT_Q_OFF   (BN)
#define OUT_R_OFF   (BN + BN * DD)
#define OUT_LOSS    (BN + 2 * BN * DD)

// ---- Scratch overlay (element offsets into S = out + OUT_Q_OFF, the
// quantized slab, 64 MB). Consumed before vq_pass2 overwrites.
#define S_LOSS      0                         // (unused; loss now in pass2)
#define S_ENORM     4                         // (reserved)
#define S_ENORM64   (S_ENORM + KC)            // KC f64 (2*KC f32 slots; 8B-aligned)
#define S_COUNT     (S_ENORM64 + 2 * KC)      // KC i32
#define S_OFFSET    (S_COUNT + KC)            // KC i32 (exclusive prefix)
#define S_BLOCKHIST (S_OFFSET + KC)           // HB*KC i32
#define S_BASE      (S_BLOCKHIST + HB * KC)   // HB*KC i32 (pre-offset)
#define S_PERM      (S_BASE + HB * KC)        // BN i32
#define S_NTIE      (S_PERM + BN)             // 1 i32 (+3 pad)
#define S_TIES      (S_NTIE + 4)              // up to BN i32
// Packed, pre-swizzled codebook: 16 tiles x 16640 B
//   per tile: [0,8K) eh swizzled | [8K,16K) el swizzled | [16K,16.25K) -en/2
#define S_EPACK     (((S_TIES + BN) + 3) & ~3)
#define TILE_BYTES  16640
#define S_PART      (S_EPACK + 16 * TILE_BYTES / 4)  // 8*KC*DD f32 reduce partials

// fp16-split dist worst-case error ~1e-4 (lo terms are 2^-23-scale; MFMA
// accumulates fp32). Margin 8e-4 keeps ~8x cushion while flagging ~2.5x
// fewer rows than the original 2e-3 (each flagged row costs a full fp64
// K-scan + 256KB of L2 emb reads in vq_resolve).
#define TIE_MARGIN 8e-4f

typedef _Float16 f16x8 __attribute__((ext_vector_type(8)));
typedef float    f32x4 __attribute__((ext_vector_type(4)));

__device__ inline f32x4 shflx4(f32x4 v, int m) {
    f32x4 r;
    r[0] = __shfl_xor(v[0], m, 64);
    r[1] = __shfl_xor(v[1], m, 64);
    r[2] = __shfl_xor(v[2], m, 64);
    r[3] = __shfl_xor(v[3], m, 64);
    return r;
}

__device__ inline void gl_lds16(const void* g, void* l) {
    __builtin_amdgcn_global_load_lds(
        (const __attribute__((address_space(1))) void*)g,
        (__attribute__((address_space(3))) void*)l, 16, 0, 0);
}

// Init (parallel, 32 blocks): 8 lanes per codebook row, one 8-elem chunk each.
// Zero loss/tie-counter, |e_k|^2 fp64 (shfl-reduced), packed pre-swizzled
// fp16 hi/lo codebook (lo scaled 2^11; swizzle = LDS layout of pass1).
__global__ __launch_bounds__(256) void vq_init(const float* __restrict__ emb,
                                               float* __restrict__ S,
                                               float* __restrict__ out_loss) {
    const int t = threadIdx.x;
    const int g = blockIdx.x * 256 + t;
    if (g == 0) { out_loss[0] = 0.0f; ((int*)(S + S_NTIE))[0] = 0; }
    const int i = g >> 3;        // codebook row (32 blocks x 256 / 8 = 1024)
    const int q = g & 7;         // 8-element chunk within the row
    const float4* e4 = (const float4*)(emb + (size_t)i * DD);
    char* tb = (char*)(S + S_EPACK) + (size_t)(i >> 6) * TILE_BYTES;
    const int ci = i & 63;
    const int sw = (ci & 7) * 8;

    float4 u = e4[2 * q], v = e4[2 * q + 1];
    float a = u.x * u.x;
    a = fmaf(u.y, u.y, a); a = fmaf(u.z, u.z, a); a = fmaf(u.w, u.w, a);
    a = fmaf(v.x, v.x, a); a = fmaf(v.y, v.y, a);
    a = fmaf(v.z, v.z, a); a = fmaf(v.w, v.w, a);
    double b = (double)u.x * u.x + (double)u.y * u.y
             + (double)u.z * u.z + (double)u.w * u.w
             + (double)v.x * v.x + (double)v.y * v.y
             + (double)v.z * v.z + (double)v.w * v.w;

    f16x8 hh, ll;
    hh[0] = (_Float16)u.x; hh[1] = (_Float16)u.y;
    hh[2] = (_Float16)u.z; hh[3] = (_Float16)u.w;
    hh[4] = (_Float16)v.x; hh[5] = (_Float16)v.y;
    hh[6] = (_Float16)v.z; hh[7] = (_Float16)v.w;
    ll[0] = (_Float16)((u.x - (float)hh[0]) * 2048.f);
    ll[1] = (_Float16)((u.y - (float)hh[1]) * 2048.f);
    ll[2] = (_Float16)((u.z - (float)hh[2]) * 2048.f);
    ll[3] = (_Float16)((u.w - (float)hh[3]) * 2048.f);
    ll[4] = (_Float16)((v.x - (float)hh[4]) * 2048.f);
    ll[5] = (_Float16)((v.y - (float)hh[5]) * 2048.f);
    ll[6] = (_Float16)((v.z - (float)hh[6]) * 2048.f);
    ll[7] = (_Float16)((v.w - (float)hh[7]) * 2048.f);
    const int u16 = (ci * 64 + q * 8) ^ sw;   // swizzled ushort idx
    *(f16x8*)(tb + 2 * u16) = hh;
    *(f16x8*)(tb + 8192 + 2 * u16) = ll;

    // reduce |e|^2 across the 8 lanes of this row (xor 1,2,4 stays in-row)
#pragma unroll
    for (int off = 1; off <= 4; off <<= 1) {
        a += __shfl_xor(a, off, 64);
        b += __shfl_xor(b, off, 64);
    }
    if (q == 0) {
        *(float*)(tb + 16384 + ci * 4) = -0.5f * a;   // MFMA C seed
        ((double*)(S + S_ENORM64))[i] = b;
    }
}

// Pass 1 (MFMA, pipelined): 4 waves/block, 32 rows/wave (128 rows/block).
// Best-measured schedule (r6/r8: 143-148us, VGPR 100, 4 blocks/CU). mi=4
// regressed (r5); min-waves bound spills (r3); fused hist regressed (r9).
// Codebook staged per 64-code tile via async global_load_lds, double buffer,
// counted vmcnt(5) + raw s_barrier (loads in flight across barrier).
// dist tracked in maximize domain m = dot - |e|^2/2 (seeded via MFMA C).
__global__ __launch_bounds__(256) void vq_pass1(
    const float* __restrict__ x,
    float* __restrict__ S,
    float* __restrict__ out_codes) {
    __shared__ __align__(16) unsigned char raw[2 * TILE_BYTES];

    const int t = threadIdx.x;
    const int lane = t & 63, wid = t >> 6;
    const int c = lane & 15, g = lane >> 4;
    const int rowbase = blockIdx.x * 128 + wid * 32;
    const char* epack = (const char*)(S + S_EPACK);

    // ---- stage tile 0 (prologue, async) ----
    {
        const char* st = epack;                 // tile 0
#pragma unroll
        for (int cc = 0; cc < 4; ++cc) {
            const int chunk = wid * 260 + cc * 64;
            gl_lds16(st + (size_t)(chunk + lane) * 16, raw + chunk * 16);
        }
        const int chunk = wid * 260 + 256;
        if (lane < 4)
            gl_lds16(st + (size_t)(chunk + lane) * 16, raw + chunk * 16);
    }

    // ---- load + convert x fragments (overlaps tile-0 staging) ----
    f16x8 a_hi[2][2], a_lo[2][2];
#pragma unroll
    for (int mi = 0; mi < 2; ++mi) {
        const float4* xr = (const float4*)(x + (size_t)(rowbase + mi * 16 + c) * DD);
#pragma unroll
        for (int h = 0; h < 2; ++h) {
            float4 u = xr[h * 8 + g * 2];
            float4 v = xr[h * 8 + g * 2 + 1];
            f16x8 hi, lo;
            hi[0] = (_Float16)u.x; hi[1] = (_Float16)u.y;
            hi[2] = (_Float16)u.z; hi[3] = (_Float16)u.w;
            hi[4] = (_Float16)v.x; hi[5] = (_Float16)v.y;
            hi[6] = (_Float16)v.z; hi[7] = (_Float16)v.w;
            lo[0] = (_Float16)((u.x - (float)hi[0]) * 2048.f);
            lo[1] = (_Float16)((u.y - (float)hi[1]) * 2048.f);
            lo[2] = (_Float16)((u.z - (float)hi[2]) * 2048.f);
            lo[3] = (_Float16)((u.w - (float)hi[3]) * 2048.f);
            lo[4] = (_Float16)((v.x - (float)hi[4]) * 2048.f);
            lo[5] = (_Float16)((v.y - (float)hi[5]) * 2048.f);
            lo[6] = (_Float16)((v.z - (float)hi[6]) * 2048.f);
            lo[7] = (_Float16)((v.w - (float)hi[7]) * 2048.f);
            a_hi[mi][h] = hi;
            a_lo[mi][h] = lo;
        }
    }

    // top-2 state in maximize domain (m bigger = closer); slot s = mi*4+r
    float b1[8], b2[8];
    int kb[8];
#pragma unroll
    for (int s = 0; s < 8; ++s) { b1[s] = -3.4e38f; b2[s] = -3.4e38f; kb[s] = 0; }

    // LDS read byte bases (swizzle folded; per-ni deltas are imm offsets)
    const int sw = (c & 7) * 8;
    const int bb0 = 2 * ((c * 64 + g * 8) ^ sw);
    const int bb1 = 2 * ((c * 64 + 32 + g * 8) ^ sw);
    const int be = 16384 + c * 4;

#pragma unroll 2
    for (int kt = 0; kt < 16; ++kt) {
        // issue next tile's staging loads, then wait for CURRENT tile only
        if (kt < 15) {
            const char* st = epack + (size_t)(kt + 1) * TILE_BYTES;
            unsigned char* db = raw + ((kt + 1) & 1) * TILE_BYTES;
#pragma unroll
            for (int cc = 0; cc < 4; ++cc) {
                const int chunk = wid * 260 + cc * 64;
                gl_lds16(st + (size_t)(chunk + lane) * 16, db + chunk * 16);
            }
            const int chunk = wid * 260 + 256;
            if (lane < 4)
                gl_lds16(st + (size_t)(chunk + lane) * 16, db + chunk * 16);
            __builtin_amdgcn_sched_barrier(0);
            asm volatile("s_waitcnt vmcnt(5)");
        } else {
            __builtin_amdgcn_sched_barrier(0);
            asm volatile("s_waitcnt vmcnt(0)");
        }
        __builtin_amdgcn_sched_barrier(0);
        __builtin_amdgcn_s_barrier();

        const unsigned char* bufp = raw + (kt & 1) * TILE_BYTES;
        const int kbase = kt * 64;
#pragma unroll
        for (int ni = 0; ni < 4; ++ni) {
            f16x8 bh0 = *(const f16x8*)(bufp + bb0 + ni * 2048);
            f16x8 bh1 = *(const f16x8*)(bufp + bb1 + ni * 2048);
            f16x8 bl0 = *(const f16x8*)(bufp + 8192 + bb0 + ni * 2048);
            f16x8 bl1 = *(const f16x8*)(bufp + 8192 + bb1 + ni * 2048);
            const float seed = *(const float*)(bufp + be + ni * 64);
            const int kcur = kbase + ni * 16 + c;
#pragma unroll
            for (int mi = 0; mi < 2; ++mi) {
                f32x4 ah = {seed, seed, seed, seed};
                f32x4 ax = {0.f, 0.f, 0.f, 0.f};
                ah = __builtin_amdgcn_mfma_f32_16x16x32_f16(a_hi[mi][0], bh0, ah, 0, 0, 0);
                ah = __builtin_amdgcn_mfma_f32_16x16x32_f16(a_hi[mi][1], bh1, ah, 0, 0, 0);
                ax = __builtin_amdgcn_mfma_f32_16x16x32_f16(a_hi[mi][0], bl0, ax, 0, 0, 0);
                ax = __builtin_amdgcn_mfma_f32_16x16x32_f16(a_lo[mi][0], bh0, ax, 0, 0, 0);
                ax = __builtin_amdgcn_mfma_f32_16x16x32_f16(a_hi[mi][1], bl1, ax, 0, 0, 0);
                ax = __builtin_amdgcn_mfma_f32_16x16x32_f16(a_lo[mi][1], bh1, ax, 0, 0, 0);
#pragma unroll
                for (int r = 0; r < 4; ++r) {
                    // m = dot - |e|^2/2  (dist = -2m)
                    const float m = fmaf(4.8828125e-4f, ax[r], ah[r]);
                    const int s = mi * 4 + r;
                    // second-best: b2' = median(m, b1, b2)  (b2 <= b1 invariant)
                    b2[s] = __builtin_amdgcn_fmed3f(m, b1[s], b2[s]);
                    const bool gt = m > b1[s];
                    b1[s] = fmaxf(b1[s], m);
                    kb[s] = gt ? kcur : kb[s];
                }
            }
        }
        __builtin_amdgcn_s_barrier();
    }

    // merge top-2 across the 16 col-lanes of each row-group (same lane>>4)
#pragma unroll
    for (int off = 1; off <= 8; off <<= 1) {
#pragma unroll
        for (int s = 0; s < 8; ++s) {
            float ob1 = __shfl_xor(b1[s], off, 64);
            float ob2 = __shfl_xor(b2[s], off, 64);
            int okk = __shfl_xor(kb[s], off, 64);
            float mn = fminf(b1[s], ob1);
            b2[s] = fmaxf(fmaxf(b2[s], ob2), mn);
            if (ob1 > b1[s]) { b1[s] = ob1; kb[s] = okk; }
        }
    }

    const int rlo = c - g * 4;   // writer lanes: c in [4g, 4g+4)
    if (rlo >= 0 && rlo < 4) {
        int* ntie = (int*)(S + S_NTIE);
        int* ties = (int*)(S + S_TIES);
#pragma unroll
        for (int mi = 0; mi < 2; ++mi) {
            const int s = mi * 4 + rlo;
            const int row = rowbase + mi * 16 + c;
            out_codes[row] = (float)kb[s];
            if ((b1[s] - b2[s]) * 2.0f < TIE_MARGIN) {
                int slot = atomicAdd(ntie, 1);
                ties[slot] = row;
            }
        }
    }
}

// Tie resolve: wave per flagged row, full fp64 argmin over K (16 codes/lane).
// Strictly stronger than candidate-limited resolve; first-k wins exact ties.
__global__ __launch_bounds__(256) void vq_resolve(
    const float* __restrict__ x,
    const float* __restrict__ emb,
    const float* __restrict__ S,
    float* __restrict__ out_codes) {
    const int n = ((const int*)(S + S_NTIE))[0];
    const int* ties = (const int*)(S + S_TIES);
    const double* en64 = (const double*)(S + S_ENORM64);
    const int lane = threadIdx.x & 63;
    const int gw = (blockIdx.x * 256 + threadIdx.x) >> 6;
    const int nw = (gridDim.x * 256) >> 6;
    for (int i = gw; i < n; i += nw) {
        const int row = ties[i];
        const float4* xr = (const float4*)(x + (size_t)row * DD);
        float4 xq[16];
#pragma unroll
        for (int j = 0; j < 16; ++j) xq[j] = xr[j];
        double bd = 1e300;
        int bk = KC;
        for (int kk = 0; kk < KC / 64; ++kk) {
            const int k = lane * (KC / 64) + kk;   // ascending within lane
            const float4* er = (const float4*)(emb + (size_t)k * DD);
            double d0 = 0., d1 = 0., d2 = 0., d3 = 0.;
#pragma unroll
            for (int j = 0; j < 16; ++j) {
                float4 e = er[j], xv = xq[j];
                d0 = fma((double)xv.x, (double)e.x, d0);
                d1 = fma((double)xv.y, (double)e.y, d1);
                d2 = fma((double)xv.z, (double)e.z, d2);
                d3 = fma((double)xv.w, (double)e.w, d3);
            }
            double dist = en64[k] - 2.0 * ((d0 + d1) + (d2 + d3));
            if (dist < bd) { bd = dist; bk = k; }
        }
#pragma unroll
        for (int off = 32; off; off >>= 1) {
            double od = __shfl_xor(bd, off, 64);
            int ok = __shfl_xor(bk, off, 64);
            if (od < bd || (od == bd && ok < bk)) { bd = od; bk = ok; }
        }
        if (lane == 0) out_codes[row] = (float)bk;
    }
}

// Histogram: per-block LDS hist over ROWS_PER_HB rows, plain-store.
__global__ __launch_bounds__(256) void vq_hist(const float* __restrict__ codes,
                                               float* S) {
    __shared__ int lh[KC];
    const int b = blockIdx.x, t = threadIdx.x;
    int* blockhist = (int*)(S + S_BLOCKHIST);
#pragma unroll
    for (int j = 0; j < 4; ++j) lh[t + 256 * j] = 0;
    __syncthreads();
#pragma unroll
    for (int j = 0; j < ROWS_PER_HB / 256; ++j) {
        int k = (int)codes[b * ROWS_PER_HB + j * 256 + t];
        atomicAdd(&lh[k], 1);   // LDS atomic
    }
    __syncthreads();
#pragma unroll
    for (int j = 0; j < 4; ++j) {
        int k = t + 256 * j;
        blockhist[b * KC + k] = lh[k];
    }
}

// Scan 1: column-parallel prefix over the HB blockhists (coalesced), and
// per-code totals. 8 blocks x 128 threads = one thread per code column.
__global__ __launch_bounds__(128) void vq_scan1(float* S) {
    const int k = blockIdx.x * 128 + threadIdx.x;
    int* blockhist = (int*)(S + S_BLOCKHIST);
    int* base      = (int*)(S + S_BASE);
    int* count     = (int*)(S + S_COUNT);
    int s = 0;
#pragma unroll 4
    for (int b = 0; b < HB; ++b) {
        base[b * KC + k] = s;            // in-block running start (pre-offset)
        s += blockhist[b * KC + k];
    }
    count[k] = s;
}

// Scan 2: exclusive prefix over K of the counts -> offset. Single block.
// (The base+offset add is folded into vq_scatter's cursor init.)
__global__ __launch_bounds__(1024) void vq_scan2(float* S) {
    __shared__ int sc[KC];
    const int k = threadIdx.x;
    int* count  = (int*)(S + S_COUNT);
    int* offset = (int*)(S + S_OFFSET);
    sc[k] = count[k];
    __syncthreads();
    for (int st = 1; st < KC; st <<= 1) {
        int v = (k >= st) ? sc[k - st] : 0;
        __syncthreads();
        sc[k] += v;
        __syncthreads();
    }
    offset[k] = (k == 0) ? 0 : sc[k - 1];  // exclusive
}

// Scatter: LDS cursors (LDS atomics only) -> perm row-index lists.
// Cursor init folds the global offset (deleting scan phase 3).
__global__ __launch_bounds__(256) void vq_scatter(const float* __restrict__ codes,
                                                  float* S) {
    __shared__ int cur[KC];
    const int b = blockIdx.x, t = threadIdx.x;
    int* base   = (int*)(S + S_BASE);
    int* offset = (int*)(S + S_OFFSET);
    int* perm   = (int*)(S + S_PERM);
#pragma unroll
    for (int j = 0; j < 4; ++j) {
        int k = t + 256 * j;
        cur[k] = base[b * KC + k] + offset[k];
    }
    __syncthreads();
#pragma unroll
    for (int j = 0; j < ROWS_PER_HB / 256; ++j) {
        int row = b * ROWS_PER_HB + j * 256 + t;
        int k = (int)codes[row];
        int slot = atomicAdd(&cur[k], 1);   // LDS atomic
        perm[slot] = row;
    }
}

// Reduce: grid = KC*8 (code k = blockIdx>>3, sub-range = blockIdx&7).
// Wave layout: 4 rows in flight (l>>4) x 16 float4 dim-segs (l&15).
// Plain-store deterministic partials to S_PART; vq_emafin combines.
__global__ __launch_bounds__(256) void vq_reduce(
    const float* __restrict__ x,
    float* __restrict__ S) {
    __shared__ f32x4 part[4][16];
    const int k = blockIdx.x >> 3, sub = blockIdx.x & 7;
    const int t = threadIdx.x, l = t & 63, w = t >> 6;
    const int rg = l >> 4, ds = l & 15;
    const int* count  = (const int*)(S + S_COUNT);
    const int* offset = (const int*)(S + S_OFFSET);
    const int* perm   = (const int*)(S + S_PERM);

    const int n = count[k], start = offset[k];
    const int nb = (n + 7) >> 3;
    int cnt = n - sub * nb;
    cnt = cnt < nb ? cnt : nb;               // may be <= 0
    const int s0 = start + sub * nb;
    const int s1 = s0 + cnt;

    f32x4 a0 = {0.f, 0.f, 0.f, 0.f}, a1 = a0, a2 = a0, a3 = a0;
    const int base = s0 + w * 4 + rg;
    const int iters = (cnt + 63) >> 6;       // uniform per block
#pragma unroll 2
    for (int it = 0; it < iters; ++it) {
        const int j = base + it * 64;
        const int r0 = (j      < s1) ? perm[j]      : -1;
        const int r1 = (j + 16 < s1) ? perm[j + 16] : -1;
        const int r2 = (j + 32 < s1) ? perm[j + 32] : -1;
        const int r3 = (j + 48 < s1) ? perm[j + 48] : -1;
        if (r0 >= 0) a0 += *(const f32x4*)(x + (size_t)r0 * DD + ds * 4);
        if (r1 >= 0) a1 += *(const f32x4*)(x + (size_t)r1 * DD + ds * 4);
        if (r2 >= 0) a2 += *(const f32x4*)(x + (size_t)r2 * DD + ds * 4);
        if (r3 >= 0) a3 += *(const f32x4*)(x + (size_t)r3 * DD + ds * 4);
    }
    f32x4 acc = (a0 + a1) + (a2 + a3);
    acc += shflx4(acc, 16);
    acc += shflx4(acc, 32);
    if (l < 16) part[w][l] = acc;
    __syncthreads();
    if (t < 16) {
        f32x4 tot = (part[0][t] + part[1][t]) + (part[2][t] + part[3][t]);
        ((f32x4*)(S + S_PART))[((size_t)sub * KC + k) * 16 + t] = tot;
    }
}

// EMA epilogue: combine 8 partials, EMA update, division, ncs.
__global__ __launch_bounds__(256) void vq_emafin(
    const float* __restrict__ S,
    const float* __restrict__ ema_cs,
    const float* __restrict__ ema_es,
    float* __restrict__ out_ne,
    float* __restrict__ out_ncs,
    float* __restrict__ out_nes) {
    const int i = blockIdx.x * 256 + threadIdx.x;
    const int* count = (const int*)(S + S_COUNT);
    const int NV = KC * DD / 4;              // 16384 float4s
    if (i < NV) {
        const f32x4* P = (const f32x4*)(S + S_PART);
        f32x4 s = ((P[i] + P[NV + i]) + (P[2 * NV + i] + P[3 * NV + i]))
                + ((P[4 * NV + i] + P[5 * NV + i]) + (P[6 * NV + i] + P[7 * NV + i]));
        f32x4 e = ((const f32x4*)ema_es)[i];
        const int k = i >> 4;
        const float cs = 0.99f * ema_cs[k] + 0.01f * (float)count[k];
        const float mx = fmaxf(cs, 1e-5f);
        f32x4 nes = e * 0.99f + s * 0.01f;
        f32x4 ne;
        ne[0] = nes[0] / mx; ne[1] = nes[1] / mx;
        ne[2] = nes[2] / mx; ne[3] = nes[3] / mx;
        ((f32x4*)out_nes)[i] = nes;
        ((f32x4*)out_ne)[i] = ne;
    } else if (i < NV + KC) {
        const int k = i - NV;
        out_ncs[k] = 0.99f * ema_cs[k] + 0.01f * (float)count[k];
    }
}

// Pass 2 (coalesced, atomic-lean): 1024 blocks x 256 rows. lane = (row-group,
// float4 seg) -> each wave access is a contiguous 1KB line; 16 deep ILP per
// thread. Loss: wave shuffle-reduce -> LDS -> ONE atomic per block.
// r7 lesson: 16384 same-address device atomics serialized (~12ns each) and
// dominated (215us, 794GB/s, VALU 1.7%). 1024 atomics hide under traffic.
__global__ __launch_bounds__(256) void vq_pass2(
    const float* __restrict__ x,
    const float* __restrict__ emb,
    const float* __restrict__ out_codes,
    float4* __restrict__ out_q,
    float4* __restrict__ out_r,
    float* __restrict__ out_loss) {
    __shared__ float lpart[4];
    const int t = threadIdx.x;
    const int seg = t & 15, rr = t >> 4;    // rr in 0..15
    const int rowbase = blockIdx.x * 256;
    float lsum = 0.f;
#pragma unroll
    for (int it = 0; it < 16; ++it) {
        const int row = rowbase + it * 16 + rr;
        const int code = (int)out_codes[row];
        const float4 xv = ((const float4*)x)[(size_t)row * 16 + seg];
        const float4 e  = ((const float4*)emb)[(size_t)code * 16 + seg];
        float4 q, r;
        q.x = xv.x + (e.x - xv.x); q.y = xv.y + (e.y - xv.y);
        q.z = xv.z + (e.z - xv.z); q.w = xv.w + (e.w - xv.w);
        r.x = xv.x - e.x; r.y = xv.y - e.y; r.z = xv.z - e.z; r.w = xv.w - e.w;
        lsum += r.x * r.x + r.y * r.y + r.z * r.z + r.w * r.w;
        out_q[(size_t)row * 16 + seg] = q;
        out_r[(size_t)row * 16 + seg] = r;
    }
#pragma unroll
    for (int off = 32; off; off >>= 1) lsum += __shfl_xor(lsum, off, 64);
    if ((t & 63) == 0) lpart[t >> 6] = lsum;
    __syncthreads();
    if (t == 0) {
        float tot = (lpart[0] + lpart[1]) + (lpart[2] + lpart[3]);
        atomicAdd(out_loss, tot * 1.25f * (1.0f / 16777216.0f));
    }
}

extern "C" void kernel_launch(void* const* d_in, const int* in_sizes, int n_in,
                              void* d_out, int out_size, void* d_ws, size_t ws_size,
                              hipStream_t stream) {
    const float* x      = (const float*)d_in[0];
    const float* emb    = (const float*)d_in[1];
    const float* ema_cs = (const float*)d_in[2];
    const float* ema_es = (const float*)d_in[3];

    float* out = (float*)d_out;
    float*  out_codes = out;
    float4* out_q     = (float4*)(out + OUT_Q_OFF);
    float4* out_r     = (float4*)(out + OUT_R_OFF);
    float*  out_loss  = out + OUT_LOSS;
    float*  out_ne    = out_loss + 1;
    float*  out_ncs   = out_ne + KC * DD;
    float*  out_nes   = out_ncs + KC;

    float* S = out + OUT_Q_OFF;   // scratch overlay in quantized slab

    vq_init<<<32, 256, 0, stream>>>(emb, S, out_loss);
    vq_pass1<<<BN / 128, 256, 0, stream>>>(x, S, out_codes);
    vq_resolve<<<256, 256, 0, stream>>>(x, emb, S, out_codes);
    vq_hist<<<HB, 256, 0, stream>>>(out_codes, S);
    vq_scan1<<<KC / 128, 128, 0, stream>>>(S);
    vq_scan2<<<1, 1024, 0, stream>>>(S);
    vq_scatter<<<HB, 256, 0, stream>>>(out_codes, S);
    vq_reduce<<<KC * 8, 256, 0, stream>>>(x, S);
    vq_emafin<<<(KC * DD / 4 + KC + 255) / 256, 256, 0, stream>>>(
        S, ema_cs, ema_es, out_ne, out_ncs, out_nes);
    vq_pass2<<<BN / 256, 256, 0, stream>>>(x, emb, out_codes, out_q, out_r,
                                           out_loss);
}